// Round 11
// baseline (631.177 us; speedup 1.0000x reference)
//
#include <hip/hip_runtime.h>
#include <hip/hip_cooperative_groups.h>

#define AANG 180
#define NN 256
#define BCH 12
#define LSTR 259
#define LROWSMAX 130
#define ACH 36

#ifndef M_PI
#define M_PI 3.14159265358979323846
#endif

namespace cg = cooperative_groups;

__device__ __forceinline__ int iclamp(int v, int lo, int hi) {
    return v < lo ? lo : (v > hi ? hi : v);
}

// LDS union: radon needs 130*259 + 2*1024 = 35718 floats (142,872 B) — the max.
#define SMEM_FLOATS (LROWSMAX * LSTR + 2 * 1024)

__global__ __launch_bounds__(1024, 4)
void fused_kernel(const float* __restrict__ x,
                  const float* __restrict__ Wq, const float* __restrict__ bq,
                  const float* __restrict__ Wk, const float* __restrict__ bk,
                  const float* __restrict__ Wv, const float* __restrict__ bv,
                  float* __restrict__ out,
                  float* __restrict__ P, float* __restrict__ Q,
                  float* __restrict__ K, float* __restrict__ Vt,
                  float* __restrict__ att_t,
                  float* __restrict__ WqT, float* __restrict__ WkT,
                  float* __restrict__ WvT) {
    __shared__ __align__(16) float smem[SMEM_FLOATS];
    cg::grid_group grid = cg::this_grid();
    int tid = threadIdx.x;
    int bid = blockIdx.x;
    const size_t HOFF = (size_t)BCH * AANG * NN;

    // ---------- P0: W transpose ----------
    {
        int idx = bid * 1024 + tid;
        if (idx < AANG * AANG) {
            int p = idx / AANG;
            int j = idx - p * AANG;
            int src = j * AANG + p;
            WqT[idx] = Wq[src];
            WkT[idx] = Wk[src];
            WvT[idx] = Wv[src];
        }
    }
    grid.sync();

    // ---------- P1: radon v9 (R8-exact math), 720 virtual blocks ----------
    {
        float* tile = smem;                       // 33670
        float* red0 = smem + LROWSMAX * LSTR;     // 1024
        float* red1 = red0 + 1024;                // 1024
        int lx = tid & 255;
        int qid = tid >> 8;
        float fx = (float)lx;
        int ubase = qid * 64;
        for (int vb = bid; vb < BCH * 2 * 30; vb += 256) {
            __syncthreads();  // prior virtual block's tile/red reads complete
            int g = vb % 30;
            int t = vb / 30;
            int h = t & 1;
            int n = t >> 1;
            int R0 = h ? 127 : -1;
            int nrows = h ? 130 : 129;
            unsigned lrmax = h ? 128u : 127u;
            const float* img = x + (size_t)n * NN * NN;
            for (int rr = qid; rr < nrows; rr += 4) {
                int gr = R0 + rr;
                bool rok = (gr >= 0) && (gr < NN);
                const float* row = img + gr * NN;
                int gc = lx - 1;
                tile[rr * LSTR + lx] = (rok && gc >= 0) ? row[gc] : 0.0f;
                if (lx < 3) {
                    int gc2 = 255 + lx;
                    tile[rr * LSTR + 256 + lx] = (rok && gc2 < NN) ? row[gc2] : 0.0f;
                }
            }
            __syncthreads();
            for (int pp = 0; pp < 3; ++pp) {
                int a0 = g + (2 * pp) * 30;
                int a1 = a0 + 30;
                float th0 = (float)((double)a0 * (M_PI / 180.0));
                float th1 = (float)((double)a1 * (M_PI / 180.0));
                float c0 = cosf(th0), s0 = sinf(th0);
                float c1 = cosf(th1), s1 = sinf(th1);
                float kx0 = -128.0f * (c0 + s0 - 1.0f), ky0 = -128.0f * (c0 - s0 - 1.0f);
                float kx1 = -128.0f * (c1 + s1 - 1.0f), ky1 = -128.0f * (c1 - s1 - 1.0f);
                float xcon0 = c0 * fx + kx0;   // sx = fma(s0, fy, xcon0)
                float dcon0 = -s0 * fx + ky0;  // sy = fma(c0, fy, dcon0)
                float xcon1 = c1 * fx + kx1;
                float dcon1 = -s1 * fx + ky1;
                float acc0 = 0.0f, acc1 = 0.0f;
#pragma unroll 4
                for (int i = 0; i < 64; ++i) {
                    float fy = (float)(ubase + i);
                    float sy0 = __builtin_fmaf(c0, fy, dcon0);
                    float sx0 = __builtin_fmaf(s0, fy, xcon0);
                    float sy1 = __builtin_fmaf(c1, fy, dcon1);
                    float sx1 = __builtin_fmaf(s1, fy, xcon1);
                    float iyf0 = floorf(sy0), ixf0 = floorf(sx0);
                    float iyf1 = floorf(sy1), ixf1 = floorf(sx1);
                    int lr0 = (int)iyf0 - R0, lc0 = (int)ixf0 + 1;
                    int lr1 = (int)iyf1 - R0, lc1 = (int)ixf1 + 1;
                    if ((unsigned)lr0 <= lrmax && (unsigned)lc0 <= 256u) {
                        float wy = sy0 - iyf0, wx = sx0 - ixf0;
                        const float* t0 = &tile[lr0 * LSTR + lc0];
                        float v00 = t0[0], v01 = t0[1];
                        float v10 = t0[LSTR], v11 = t0[LSTR + 1];
                        float wx1 = 1.0f - wx, wy1 = 1.0f - wy;
                        acc0 += wy1 * (wx1 * v00 + wx * v01) + wy * (wx1 * v10 + wx * v11);
                    }
                    if ((unsigned)lr1 <= lrmax && (unsigned)lc1 <= 256u) {
                        float wy = sy1 - iyf1, wx = sx1 - ixf1;
                        const float* t1 = &tile[lr1 * LSTR + lc1];
                        float v00 = t1[0], v01 = t1[1];
                        float v10 = t1[LSTR], v11 = t1[LSTR + 1];
                        float wx1 = 1.0f - wx, wy1 = 1.0f - wy;
                        acc1 += wy1 * (wx1 * v00 + wx * v01) + wy * (wx1 * v10 + wx * v11);
                    }
                }
                if (pp) __syncthreads();
                red0[tid] = acc0;
                red1[tid] = acc1;
                __syncthreads();
                if (tid < 256) {
                    float r0 = red0[tid] + red0[tid + 256] + red0[tid + 512] + red0[tid + 768];
                    float r1 = red1[tid] + red1[tid + 256] + red1[tid + 512] + red1[tid + 768];
                    size_t base = (((size_t)h * BCH + n) * AANG);
                    P[(base + a0) * NN + tid] = r0;
                    P[(base + a1) * NN + tid] = r1;
                }
            }
        }
    }
    grid.sync();

    // ---------- P2: qkv, 768 virtual 4-row sub-blocks (4 per real block) ----------
    {
        float* srow = smem;  // [4][AANG][4] = 2880 floats
        int sb = tid >> 8;
        int t2 = tid & 255;
        int vb = bid * 4 + sb;
        bool valid = vb < BCH * 64;
        int n = vb >> 6;
        int i0 = (vb & 63) * 4;
        if (valid && t2 < AANG) {
            size_t idx = (((size_t)n) * AANG + t2) * NN + i0;
            float4 p0 = *(const float4*)&P[idx];
            float4 q0 = *(const float4*)&P[idx + HOFF];
            float* sr = &srow[(sb * AANG + t2) * 4];
            sr[0] = p0.x + q0.x;
            sr[1] = p0.y + q0.y;
            sr[2] = p0.z + q0.z;
            sr[3] = p0.w + q0.w;
        }
        __syncthreads();
        if (valid && t2 < AANG) {
            int j = t2;
            float aq[4], ak[4], av[4];
            float bqv = bq[j], bkv = bk[j], bvv = bv[j];
#pragma unroll
            for (int r = 0; r < 4; ++r) { aq[r] = bqv; ak[r] = bkv; av[r] = bvv; }
#pragma unroll 4
            for (int p = 0; p < AANG; ++p) {
                float wq = WqT[p * AANG + j];
                float wk = WkT[p * AANG + j];
                float wv = WvT[p * AANG + j];
                float4 sv = *(const float4*)&srow[(sb * AANG + p) * 4];
                aq[0] += sv.x * wq; ak[0] += sv.x * wk; av[0] += sv.x * wv;
                aq[1] += sv.y * wq; ak[1] += sv.y * wk; av[1] += sv.y * wv;
                aq[2] += sv.z * wq; ak[2] += sv.z * wk; av[2] += sv.z * wv;
                aq[3] += sv.w * wq; ak[3] += sv.w * wk; av[3] += sv.w * wv;
            }
#pragma unroll
            for (int r = 0; r < 4; ++r) {
                size_t qb = ((size_t)(n * NN + i0 + r)) * AANG + j;
                Q[qb] = aq[r];
                K[qb] = ak[r];
            }
            size_t vbo = ((size_t)(n * AANG + j)) * NN + i0;
            *(float4*)&Vt[vbo] = make_float4(av[0], av[1], av[2], av[3]);
        }
    }
    grid.sync();

    // ---------- P3: attention, 768 virtual 4-row sub-blocks ----------
    {
        float* qrow = smem;                  // [4][4][AANG] = 2880
        float* prob = smem + 2880;           // [4][4][NN] = 4096
        float* wm   = smem + 2880 + 4096;    // [4][4][4] = 64
        float* wsm  = wm + 64;               // 64
        int sb = tid >> 8;
        int t2 = tid & 255;
        int vb = bid * 4 + sb;
        bool valid = vb < BCH * 64;
        int n = vb >> 6;
        int i0 = (vb & 63) * 4;
        int sw = t2 >> 6;  // wave within sub-block
        if (valid && t2 < AANG) {
#pragma unroll
            for (int r = 0; r < 4; ++r)
                qrow[(sb * 4 + r) * AANG + t2] = Q[((size_t)(n * NN + i0 + r)) * AANG + t2];
        }
        __syncthreads();
        float d[4] = {0.0f, 0.0f, 0.0f, 0.0f};
        if (valid) {
            const float* krow = K + ((size_t)(n * NN) + t2) * AANG;
#pragma unroll 3
            for (int jj = 0; jj < AANG / 4; ++jj) {
                float4 kv = *(const float4*)&krow[jj * 4];
#pragma unroll
                for (int r = 0; r < 4; ++r) {
                    float4 qv = *(const float4*)&qrow[(sb * 4 + r) * AANG + jj * 4];
                    d[r] += qv.x * kv.x;
                    d[r] += qv.y * kv.y;
                    d[r] += qv.z * kv.z;
                    d[r] += qv.w * kv.w;
                }
            }
        }
        const float rs = 0.0745355992f;  // 1/sqrt(180)
        float l[4], m[4], e[4], s[4];
#pragma unroll
        for (int r = 0; r < 4; ++r) { l[r] = d[r] * rs; m[r] = l[r]; }
        for (int off = 32; off > 0; off >>= 1) {
#pragma unroll
            for (int r = 0; r < 4; ++r) m[r] = fmaxf(m[r], __shfl_xor(m[r], off));
        }
        if (valid && (t2 & 63) == 0) {
#pragma unroll
            for (int r = 0; r < 4; ++r) wm[(sb * 4 + r) * 4 + sw] = m[r];
        }
        __syncthreads();
#pragma unroll
        for (int r = 0; r < 4; ++r) {
            const float* w = &wm[(sb * 4 + r) * 4];
            float mx = fmaxf(fmaxf(w[0], w[1]), fmaxf(w[2], w[3]));
            e[r] = expf(l[r] - mx);
            s[r] = e[r];
        }
        for (int off = 32; off > 0; off >>= 1) {
#pragma unroll
            for (int r = 0; r < 4; ++r) s[r] += __shfl_xor(s[r], off);
        }
        if (valid && (t2 & 63) == 0) {
#pragma unroll
            for (int r = 0; r < 4; ++r) wsm[(sb * 4 + r) * 4 + sw] = s[r];
        }
        __syncthreads();
        if (valid) {
#pragma unroll
            for (int r = 0; r < 4; ++r) {
                const float* w = &wsm[(sb * 4 + r) * 4];
                float dn = w[0] + w[1] + w[2] + w[3];
                prob[(sb * 4 + r) * NN + t2] = e[r] / dn;
            }
        }
        __syncthreads();
        if (valid && t2 < AANG) {
            float a[4] = {0.0f, 0.0f, 0.0f, 0.0f};
            const float* vrow = Vt + ((size_t)(n * AANG) + t2) * NN;
#pragma unroll 4
            for (int kk = 0; kk < NN / 4; ++kk) {
                float4 v4 = *(const float4*)&vrow[kk * 4];
#pragma unroll
                for (int r = 0; r < 4; ++r) {
                    float4 p4 = *(const float4*)&prob[(sb * 4 + r) * NN + kk * 4];
                    a[r] += p4.x * v4.x;
                    a[r] += p4.y * v4.y;
                    a[r] += p4.z * v4.z;
                    a[r] += p4.w * v4.w;
                }
            }
            size_t ob = ((size_t)(n * AANG + t2)) * NN + i0;
            *(float4*)&att_t[ob] = make_float4(a[0], a[1], a[2], a[3]);
        }
    }
    grid.sync();

    // ---------- P4: ramp filter, 2160 columns over 3 uniform passes ----------
    {
        float* coef  = smem;         // 128
        float* scolb = smem + 128;   // 4*512
        int sb = tid >> 8;
        int t2 = tid & 255;
        if (tid < 128) {
            float dd = (float)(2 * tid + 1);
            coef[tid] = -2.0f / ((float)(M_PI * M_PI) * dd * dd);
        }
        float* scol = scolb + sb * 512;
        for (int k = 0; k < 3; ++k) {
            int vb = bid * 4 + sb + k * 1024;
            bool valid = vb < BCH * AANG;
            __syncthreads();  // publishes coef on k=0; guards scol reuse after
            if (valid) {
                const float* src = &att_t[(size_t)vb * NN];
                scol[t2] = (t2 >= 128) ? src[t2 - 128] : 0.0f;
                scol[t2 + 256] = (t2 < 128) ? src[t2 + 128] : 0.0f;
            }
            __syncthreads();
            if (valid) {
                const float* c = &scol[t2 + 128];
                float acc = 0.5f * c[0];
#pragma unroll 4
                for (int mm = 0; mm < 128; ++mm) {
                    int dd = 2 * mm + 1;
                    acc += coef[mm] * (c[-dd] + c[dd]);
                }
                P[(size_t)vb * NN + t2] = acc;  // filt aliases P (partials dead)
            }
        }
    }
    grid.sync();

    // ---------- P5: backprojection, 768 virtual blocks (exactly 3 per real) ----------
    {
        float* cols = smem;                // [ACH][NN] = 9216
        float* cs   = smem + ACH * NN;     // 180
        float* sn   = cs + AANG;           // 180
        int col = tid & 255;
        int rslot = tid >> 8;
        if (tid < AANG) {
            float th = (float)((double)tid * (M_PI / 180.0));
            cs[tid] = cosf(th);
            sn[tid] = sinf(th);
        }
        float yr = (float)(col - 128);
        for (int vb = bid; vb < BCH * 64; vb += 256) {
            int n = vb >> 6;
            int rg = vb & 63;
            int r = rg * 4 + rslot;
            float xr = (float)(r - 128);
            float acc = 0.0f;
            const float* fb = P + (size_t)n * AANG * NN;
            for (int ch = 0; ch < AANG / ACH; ++ch) {
                __syncthreads();
                for (int idx = tid; idx < ACH * NN; idx += 1024) {
                    int q = idx >> 8;
                    int cc = idx & 255;
                    cols[q * NN + cc] = fb[(size_t)(ch * ACH + q) * NN + cc];
                }
                __syncthreads();
#pragma unroll 4
                for (int q = 0; q < ACH; ++q) {
                    int aa = ch * ACH + q;
                    float t = yr * cs[aa] - xr * sn[aa] + 128.0f;
                    float i0f = floorf(t);
                    int i0 = (int)i0f;
                    float frac = t - i0f;
                    int c0 = iclamp(i0, 0, NN - 1);
                    int c1 = iclamp(i0 + 1, 0, NN - 1);
                    float val = (1.0f - frac) * cols[q * NN + c0] + frac * cols[q * NN + c1];
                    if (t >= 0.0f && t <= 255.0f) acc += val;
                }
            }
            bool inside = (xr * xr + yr * yr) <= 16384.0f;
            out[((size_t)(n * NN + r)) * NN + col] = inside ? acc * (float)(M_PI / 360.0) : 0.0f;
        }
    }
}

extern "C" void kernel_launch(void* const* d_in, const int* in_sizes, int n_in,
                              void* d_out, int out_size, void* d_ws, size_t ws_size,
                              hipStream_t stream) {
    const float* x  = (const float*)d_in[0];
    const float* Wq = (const float*)d_in[1];
    const float* bq = (const float*)d_in[2];
    const float* Wk = (const float*)d_in[3];
    const float* bk = (const float*)d_in[4];
    const float* Wv = (const float*)d_in[5];
    const float* bv = (const float*)d_in[6];
    float* out = (float*)d_out;
    float* ws = (float*)d_ws;

    const size_t SZ = (size_t)BCH * NN * AANG;
    float* P     = ws;           // partial[2][n][a][x]; later aliased as filt
    float* Q     = P + 2 * SZ;
    float* K     = Q + SZ;       // row-major, same layout as Q
    float* Vt    = K + SZ;       // transposed: Vt[n][j][i]
    float* att_t = Vt + SZ;
    float* WqT   = att_t;        // alias: W-transposes dead before attn writes att_t
    float* WkT   = WqT + AANG * AANG;
    float* WvT   = WkT + AANG * AANG;

    void* args[] = {
        (void*)&x, (void*)&Wq, (void*)&bq, (void*)&Wk, (void*)&bk,
        (void*)&Wv, (void*)&bv, (void*)&out, (void*)&P, (void*)&Q,
        (void*)&K, (void*)&Vt, (void*)&att_t, (void*)&WqT, (void*)&WkT,
        (void*)&WvT
    };
    hipLaunchCooperativeKernel((void*)fused_kernel, dim3(256), dim3(1024),
                               args, 0, stream);
}

// Round 12
// 462.950 us; speedup vs baseline: 1.3634x; 1.3634x over previous
//
#include <hip/hip_runtime.h>

#define AANG 180
#define NN 256
#define BCH 12

#ifndef M_PI
#define M_PI 3.14159265358979323846
#endif

__device__ __forceinline__ int iclamp(int v, int lo, int hi) {
    return v < lo ? lo : (v > hi ? hi : v);
}

// ---------------- Radon v9 (R8-exact math) + wtrans prologue.
// Half-image LDS residency, dual-angle ILP, unroll-4, unsigned-range predicates.
// Do NOT touch the per-sample FP expressions (floor discontinuities -> softmax flips).
#define LSTR 259
#define LROWSMAX 130

__global__ __launch_bounds__(1024, 1)
void radon_kernel(const float* __restrict__ x, float* __restrict__ partial,
                  const float* __restrict__ Wq, const float* __restrict__ Wk,
                  const float* __restrict__ Wv, float* __restrict__ WqT,
                  float* __restrict__ WkT, float* __restrict__ WvT) {
    __shared__ float tile[LROWSMAX * LSTR];  // 134,680 B
    __shared__ float red[2][1024];           // + 8 KB
    int blk = blockIdx.x;        // ((n*2)+h)*30 + g
    int tid = threadIdx.x;

    // --- wtrans prologue: 720 blocks x 45 elements = 32400 (exact) ---
    if (tid < 45) {
        int idx = blk * 45 + tid;
        int p = idx / AANG;
        int j = idx - p * AANG;
        int src = j * AANG + p;
        WqT[idx] = Wq[src];
        WkT[idx] = Wk[src];
        WvT[idx] = Wv[src];
    }

    int g = blk % 30;
    int t = blk / 30;
    int h = t & 1;
    int n = t >> 1;
    int lx = tid & 255;
    int qid = tid >> 8;
    int R0 = h ? 127 : -1;
    int nrows = h ? 130 : 129;
    unsigned lrmax = h ? 128u : 127u;  // valid lr in [0, lrmax]
    const float* img = x + (size_t)n * NN * NN;

    for (int rr = qid; rr < nrows; rr += 4) {
        int gr = R0 + rr;
        bool rok = (gr >= 0) && (gr < NN);
        const float* row = img + gr * NN;
        int gc = lx - 1;
        tile[rr * LSTR + lx] = (rok && gc >= 0) ? row[gc] : 0.0f;
        if (lx < 3) {
            int gc2 = 255 + lx;
            tile[rr * LSTR + 256 + lx] = (rok && gc2 < NN) ? row[gc2] : 0.0f;
        }
    }
    __syncthreads();

    float fx = (float)lx;
    int ubase = qid * 64;

    for (int pp = 0; pp < 3; ++pp) {
        int a0 = g + (2 * pp) * 30;
        int a1 = a0 + 30;
        float th0 = (float)((double)a0 * (M_PI / 180.0));
        float th1 = (float)((double)a1 * (M_PI / 180.0));
        float c0 = cosf(th0), s0 = sinf(th0);
        float c1 = cosf(th1), s1 = sinf(th1);
        float kx0 = -128.0f * (c0 + s0 - 1.0f), ky0 = -128.0f * (c0 - s0 - 1.0f);
        float kx1 = -128.0f * (c1 + s1 - 1.0f), ky1 = -128.0f * (c1 - s1 - 1.0f);
        float xcon0 = c0 * fx + kx0;   // sx = fma(s0, fy, xcon0)
        float dcon0 = -s0 * fx + ky0;  // sy = fma(c0, fy, dcon0)
        float xcon1 = c1 * fx + kx1;
        float dcon1 = -s1 * fx + ky1;
        float acc0 = 0.0f, acc1 = 0.0f;
#pragma unroll 4
        for (int i = 0; i < 64; ++i) {
            float fy = (float)(ubase + i);
            float sy0 = __builtin_fmaf(c0, fy, dcon0);
            float sx0 = __builtin_fmaf(s0, fy, xcon0);
            float sy1 = __builtin_fmaf(c1, fy, dcon1);
            float sx1 = __builtin_fmaf(s1, fy, xcon1);
            float iyf0 = floorf(sy0), ixf0 = floorf(sx0);
            float iyf1 = floorf(sy1), ixf1 = floorf(sx1);
            int lr0 = (int)iyf0 - R0, lc0 = (int)ixf0 + 1;
            int lr1 = (int)iyf1 - R0, lc1 = (int)ixf1 + 1;
            if ((unsigned)lr0 <= lrmax && (unsigned)lc0 <= 256u) {
                float wy = sy0 - iyf0, wx = sx0 - ixf0;
                const float* t0 = &tile[lr0 * LSTR + lc0];
                float v00 = t0[0], v01 = t0[1];
                float v10 = t0[LSTR], v11 = t0[LSTR + 1];
                float wx1 = 1.0f - wx, wy1 = 1.0f - wy;
                acc0 += wy1 * (wx1 * v00 + wx * v01) + wy * (wx1 * v10 + wx * v11);
            }
            if ((unsigned)lr1 <= lrmax && (unsigned)lc1 <= 256u) {
                float wy = sy1 - iyf1, wx = sx1 - ixf1;
                const float* t1 = &tile[lr1 * LSTR + lc1];
                float v00 = t1[0], v01 = t1[1];
                float v10 = t1[LSTR], v11 = t1[LSTR + 1];
                float wx1 = 1.0f - wx, wy1 = 1.0f - wy;
                acc1 += wy1 * (wx1 * v00 + wx * v01) + wy * (wx1 * v10 + wx * v11);
            }
        }
        if (pp) __syncthreads();
        red[0][tid] = acc0;
        red[1][tid] = acc1;
        __syncthreads();
        if (tid < 256) {
            float r0 = red[0][tid] + red[0][tid + 256] + red[0][tid + 512] + red[0][tid + 768];
            float r1 = red[1][tid] + red[1][tid + 256] + red[1][tid + 512] + red[1][tid + 768];
            size_t base = (((size_t)h * BCH + n) * AANG);
            partial[(base + a0) * NN + tid] = r0;
            partial[(base + a1) * NN + tid] = r1;
        }
    }
}

// ---------------- QKV v5: 4 rows/block, 768 blocks (3 blocks/CU).
// Layout wins kept: float4 partial loads, b128 srow broadcast, K row-major, Vt.
__global__ void qkv_kernel(const float* __restrict__ partial,
                           const float* __restrict__ WqT, const float* __restrict__ bq,
                           const float* __restrict__ WkT, const float* __restrict__ bk,
                           const float* __restrict__ WvT, const float* __restrict__ bv,
                           float* __restrict__ Q, float* __restrict__ K,
                           float* __restrict__ Vt) {
    __shared__ float srow_t[AANG][4];
    int blk = blockIdx.x;  // n*64 + i4
    int n = blk >> 6;
    int i0 = (blk & 63) * 4;
    int tid = threadIdx.x;  // 256
    const size_t HOFF = (size_t)BCH * AANG * NN;
    if (tid < AANG) {
        size_t idx = (((size_t)n) * AANG + tid) * NN + i0;
        float4 p0 = *(const float4*)&partial[idx];
        float4 q0 = *(const float4*)&partial[idx + HOFF];
        srow_t[tid][0] = p0.x + q0.x;
        srow_t[tid][1] = p0.y + q0.y;
        srow_t[tid][2] = p0.z + q0.z;
        srow_t[tid][3] = p0.w + q0.w;
    }
    __syncthreads();
    if (tid < AANG) {
        int j = tid;
        float aq[4], ak[4], av[4];
        float bqv = bq[j], bkv = bk[j], bvv = bv[j];
#pragma unroll
        for (int r = 0; r < 4; ++r) { aq[r] = bqv; ak[r] = bkv; av[r] = bvv; }
#pragma unroll 4
        for (int p = 0; p < AANG; ++p) {
            float wq = WqT[p * AANG + j];
            float wk = WkT[p * AANG + j];
            float wv = WvT[p * AANG + j];
            float4 sv = *(const float4*)&srow_t[p][0];
            aq[0] += sv.x * wq; ak[0] += sv.x * wk; av[0] += sv.x * wv;
            aq[1] += sv.y * wq; ak[1] += sv.y * wk; av[1] += sv.y * wv;
            aq[2] += sv.z * wq; ak[2] += sv.z * wk; av[2] += sv.z * wv;
            aq[3] += sv.w * wq; ak[3] += sv.w * wk; av[3] += sv.w * wv;
        }
#pragma unroll
        for (int r = 0; r < 4; ++r) {
            size_t qb = ((size_t)(n * NN + i0 + r)) * AANG + j;
            Q[qb] = aq[r];  // coalesced over j
            K[qb] = ak[r];  // row-major, coalesced over j
        }
        size_t vb = ((size_t)(n * AANG + j)) * NN + i0;
        *(float4*)&Vt[vb] = make_float4(av[0], av[1], av[2], av[3]);
    }
}

// ---------------- Attention v5: 4 rows/block, 768 blocks; K row-major float4
// streams, Vt float4 streams, b128 LDS broadcasts. Bit-identical to R10 math.
__global__ void attn_kernel(const float* __restrict__ Q, const float* __restrict__ K,
                            const float* __restrict__ Vt, float* __restrict__ att_t) {
    __shared__ float qrow[4][AANG];   // 720 B row stride (16B-aligned)
    __shared__ float prob[4][NN];
    __shared__ float wm[4][4], wsm[4][4];
    int blk = blockIdx.x;  // n*64 + i4
    int n = blk >> 6;
    int i0 = (blk & 63) * 4;
    int tid = threadIdx.x;  // 256: key index k
    int wid = tid >> 6;
    if (tid < AANG) {
#pragma unroll
        for (int r = 0; r < 4; ++r)
            qrow[r][tid] = Q[((size_t)(n * NN + i0 + r)) * AANG + tid];
    }
    __syncthreads();
    float d[4] = {0.0f, 0.0f, 0.0f, 0.0f};
    const float* krow = K + ((size_t)(n * NN) + tid) * AANG;  // this key's row
#pragma unroll 3
    for (int jj = 0; jj < AANG / 4; ++jj) {
        float4 kv = *(const float4*)&krow[jj * 4];
#pragma unroll
        for (int r = 0; r < 4; ++r) {
            float4 qv = *(const float4*)&qrow[r][jj * 4];
            d[r] += qv.x * kv.x;
            d[r] += qv.y * kv.y;
            d[r] += qv.z * kv.z;
            d[r] += qv.w * kv.w;
        }
    }
    const float rs = 0.0745355992f;  // 1/sqrt(180)
    float l[4], m[4], e[4], s[4];
#pragma unroll
    for (int r = 0; r < 4; ++r) { l[r] = d[r] * rs; m[r] = l[r]; }
    for (int off = 32; off > 0; off >>= 1) {
#pragma unroll
        for (int r = 0; r < 4; ++r) m[r] = fmaxf(m[r], __shfl_xor(m[r], off));
    }
    if ((tid & 63) == 0) {
#pragma unroll
        for (int r = 0; r < 4; ++r) wm[r][wid] = m[r];
    }
    __syncthreads();
#pragma unroll
    for (int r = 0; r < 4; ++r) {
        float mx = fmaxf(fmaxf(wm[r][0], wm[r][1]), fmaxf(wm[r][2], wm[r][3]));
        e[r] = expf(l[r] - mx);
        s[r] = e[r];
    }
    for (int off = 32; off > 0; off >>= 1) {
#pragma unroll
        for (int r = 0; r < 4; ++r) s[r] += __shfl_xor(s[r], off);
    }
    if ((tid & 63) == 0) {
#pragma unroll
        for (int r = 0; r < 4; ++r) wsm[r][wid] = s[r];
    }
    __syncthreads();
#pragma unroll
    for (int r = 0; r < 4; ++r) {
        float dn = wsm[r][0] + wsm[r][1] + wsm[r][2] + wsm[r][3];
        prob[r][tid] = e[r] / dn;
    }
    __syncthreads();
    if (tid < AANG) {
        float a[4] = {0.0f, 0.0f, 0.0f, 0.0f};
        const float* vrow = Vt + ((size_t)(n * AANG) + tid) * NN;  // this j's row
#pragma unroll 4
        for (int kk = 0; kk < NN / 4; ++kk) {
            float4 v4 = *(const float4*)&vrow[kk * 4];
#pragma unroll
            for (int r = 0; r < 4; ++r) {
                float4 p4 = *(const float4*)&prob[r][kk * 4];
                a[r] += p4.x * v4.x;
                a[r] += p4.y * v4.y;
                a[r] += p4.z * v4.z;
                a[r] += p4.w * v4.w;
            }
        }
        size_t ob = ((size_t)(n * AANG + tid)) * NN + i0;
        *(float4*)&att_t[ob] = make_float4(a[0], a[1], a[2], a[3]);
    }
}

// ---------------- Ramp filter v2: zero-padded scol, no boundary selects. ----
__global__ void filter_kernel(const float* __restrict__ att_t, float* __restrict__ filt) {
    __shared__ float scol[512];  // [128..383] = data, rest 0
    __shared__ float coef[128];
    int blk = blockIdx.x;  // n*AANG + a
    int tid = threadIdx.x;
    const float* src = &att_t[(size_t)blk * NN];
    scol[tid] = (tid >= 128) ? src[tid - 128] : 0.0f;
    scol[tid + 256] = (tid < 128) ? src[tid + 128] : 0.0f;
    if (tid < 128) {
        float d = (float)(2 * tid + 1);
        coef[tid] = -2.0f / ((float)(M_PI * M_PI) * d * d);
    }
    __syncthreads();
    const float* c = &scol[tid + 128];
    float acc = 0.5f * c[0];
#pragma unroll 4
    for (int m = 0; m < 128; ++m) {
        int d = 2 * m + 1;
        acc += coef[m] * (c[-d] + c[d]);
    }
    filt[(size_t)blk * NN + tid] = acc;
}

// ---------------- Backprojection v3 (R8-exact): block = (n, 4-row group);
// 1024 threads; 36-angle chunks staged cooperatively. ----
#define ACH 36
__global__ __launch_bounds__(1024)
void backproj_kernel(const float* __restrict__ filt, float* __restrict__ out) {
    __shared__ float cols[ACH][NN];
    __shared__ float cs[AANG], sn[AANG];
    int blk = blockIdx.x;  // n*64 + rg
    int n = blk >> 6;
    int rg = blk & 63;
    int tid = threadIdx.x;
    int col = tid & 255;
    int rslot = tid >> 8;
    int r = rg * 4 + rslot;
    if (tid < AANG) {
        float th = (float)((double)tid * (M_PI / 180.0));
        cs[tid] = cosf(th);
        sn[tid] = sinf(th);
    }
    float xr = (float)(r - 128);
    float yr = (float)(col - 128);
    float acc = 0.0f;
    const float* fb = filt + (size_t)n * AANG * NN;
    for (int ch = 0; ch < AANG / ACH; ++ch) {
        __syncthreads();
        for (int idx = tid; idx < ACH * NN; idx += 1024) {
            int q = idx >> 8;
            int cc = idx & 255;
            cols[q][cc] = fb[(size_t)(ch * ACH + q) * NN + cc];
        }
        __syncthreads();
#pragma unroll 4
        for (int q = 0; q < ACH; ++q) {
            int aa = ch * ACH + q;
            float t = yr * cs[aa] - xr * sn[aa] + 128.0f;
            float i0f = floorf(t);
            int i0 = (int)i0f;
            float frac = t - i0f;
            int c0 = iclamp(i0, 0, NN - 1);
            int c1 = iclamp(i0 + 1, 0, NN - 1);
            float val = (1.0f - frac) * cols[q][c0] + frac * cols[q][c1];
            if (t >= 0.0f && t <= 255.0f) acc += val;
        }
    }
    bool inside = (xr * xr + yr * yr) <= 16384.0f;
    out[((size_t)(n * NN + r)) * NN + col] = inside ? acc * (float)(M_PI / 360.0) : 0.0f;
}

extern "C" void kernel_launch(void* const* d_in, const int* in_sizes, int n_in,
                              void* d_out, int out_size, void* d_ws, size_t ws_size,
                              hipStream_t stream) {
    const float* x  = (const float*)d_in[0];
    const float* Wq = (const float*)d_in[1];
    const float* bq = (const float*)d_in[2];
    const float* Wk = (const float*)d_in[3];
    const float* bk = (const float*)d_in[4];
    const float* Wv = (const float*)d_in[5];
    const float* bv = (const float*)d_in[6];
    float* out = (float*)d_out;
    float* ws = (float*)d_ws;

    const size_t SZ = (size_t)BCH * NN * AANG;
    float* P     = ws;           // partial[2][n][a][x]
    float* Q     = P + 2 * SZ;
    float* K     = Q + SZ;       // row-major, same layout as Q
    float* Vt    = K + SZ;       // transposed: Vt[n][j][i]
    float* att_t = Vt + SZ;
    float* WqT   = att_t;        // alias: W-transposes dead before attn writes att_t
    float* WkT   = WqT + AANG * AANG;
    float* WvT   = WkT + AANG * AANG;
    float* filt  = P;            // alias: partials dead after qkv

    radon_kernel<<<BCH * 2 * 30, 1024, 0, stream>>>(x, P, Wq, Wk, Wv, WqT, WkT, WvT);
    qkv_kernel<<<BCH * (NN / 4), 256, 0, stream>>>(P, WqT, bq, WkT, bk, WvT, bv, Q, K, Vt);
    attn_kernel<<<BCH * (NN / 4), 256, 0, stream>>>(Q, K, Vt, att_t);
    filter_kernel<<<BCH * AANG, NN, 0, stream>>>(att_t, filt);
    backproj_kernel<<<BCH * (NN / 4), 1024, 0, stream>>>(filt, out);
}

// Round 13
// 442.040 us; speedup vs baseline: 1.4279x; 1.0473x over previous
//
#include <hip/hip_runtime.h>

#define AANG 180
#define NN 256
#define BCH 12

#ifndef M_PI
#define M_PI 3.14159265358979323846
#endif

__device__ __forceinline__ int iclamp(int v, int lo, int hi) {
    return v < lo ? lo : (v > hi ? hi : v);
}

// ---------------- Radon v9 (R8-exact math) + wtrans prologue.
// Half-image LDS residency, dual-angle ILP, unroll-4, unsigned-range predicates.
// Do NOT touch the per-sample FP expressions (floor discontinuities -> softmax flips).
#define LSTR 259
#define LROWSMAX 130

__global__ __launch_bounds__(1024, 1)
void radon_kernel(const float* __restrict__ x, float* __restrict__ partial,
                  const float* __restrict__ Wq, const float* __restrict__ Wk,
                  const float* __restrict__ Wv, float* __restrict__ WqT,
                  float* __restrict__ WkT, float* __restrict__ WvT) {
    __shared__ float tile[LROWSMAX * LSTR];  // 134,680 B
    __shared__ float red[2][1024];           // + 8 KB
    int blk = blockIdx.x;        // ((n*2)+h)*30 + g
    int tid = threadIdx.x;

    // --- wtrans prologue: 720 blocks x 45 elements = 32400 (exact) ---
    if (tid < 45) {
        int idx = blk * 45 + tid;
        int p = idx / AANG;
        int j = idx - p * AANG;
        int src = j * AANG + p;
        WqT[idx] = Wq[src];
        WkT[idx] = Wk[src];
        WvT[idx] = Wv[src];
    }

    int g = blk % 30;
    int t = blk / 30;
    int h = t & 1;
    int n = t >> 1;
    int lx = tid & 255;
    int qid = tid >> 8;
    int R0 = h ? 127 : -1;
    int nrows = h ? 130 : 129;
    unsigned lrmax = h ? 128u : 127u;  // valid lr in [0, lrmax]
    const float* img = x + (size_t)n * NN * NN;

    for (int rr = qid; rr < nrows; rr += 4) {
        int gr = R0 + rr;
        bool rok = (gr >= 0) && (gr < NN);
        const float* row = img + gr * NN;
        int gc = lx - 1;
        tile[rr * LSTR + lx] = (rok && gc >= 0) ? row[gc] : 0.0f;
        if (lx < 3) {
            int gc2 = 255 + lx;
            tile[rr * LSTR + 256 + lx] = (rok && gc2 < NN) ? row[gc2] : 0.0f;
        }
    }
    __syncthreads();

    float fx = (float)lx;
    int ubase = qid * 64;

    for (int pp = 0; pp < 3; ++pp) {
        int a0 = g + (2 * pp) * 30;
        int a1 = a0 + 30;
        float th0 = (float)((double)a0 * (M_PI / 180.0));
        float th1 = (float)((double)a1 * (M_PI / 180.0));
        float c0 = cosf(th0), s0 = sinf(th0);
        float c1 = cosf(th1), s1 = sinf(th1);
        float kx0 = -128.0f * (c0 + s0 - 1.0f), ky0 = -128.0f * (c0 - s0 - 1.0f);
        float kx1 = -128.0f * (c1 + s1 - 1.0f), ky1 = -128.0f * (c1 - s1 - 1.0f);
        float xcon0 = c0 * fx + kx0;   // sx = fma(s0, fy, xcon0)
        float dcon0 = -s0 * fx + ky0;  // sy = fma(c0, fy, dcon0)
        float xcon1 = c1 * fx + kx1;
        float dcon1 = -s1 * fx + ky1;
        float acc0 = 0.0f, acc1 = 0.0f;
#pragma unroll 4
        for (int i = 0; i < 64; ++i) {
            float fy = (float)(ubase + i);
            float sy0 = __builtin_fmaf(c0, fy, dcon0);
            float sx0 = __builtin_fmaf(s0, fy, xcon0);
            float sy1 = __builtin_fmaf(c1, fy, dcon1);
            float sx1 = __builtin_fmaf(s1, fy, xcon1);
            float iyf0 = floorf(sy0), ixf0 = floorf(sx0);
            float iyf1 = floorf(sy1), ixf1 = floorf(sx1);
            int lr0 = (int)iyf0 - R0, lc0 = (int)ixf0 + 1;
            int lr1 = (int)iyf1 - R0, lc1 = (int)ixf1 + 1;
            if ((unsigned)lr0 <= lrmax && (unsigned)lc0 <= 256u) {
                float wy = sy0 - iyf0, wx = sx0 - ixf0;
                const float* t0 = &tile[lr0 * LSTR + lc0];
                float v00 = t0[0], v01 = t0[1];
                float v10 = t0[LSTR], v11 = t0[LSTR + 1];
                float wx1 = 1.0f - wx, wy1 = 1.0f - wy;
                acc0 += wy1 * (wx1 * v00 + wx * v01) + wy * (wx1 * v10 + wx * v11);
            }
            if ((unsigned)lr1 <= lrmax && (unsigned)lc1 <= 256u) {
                float wy = sy1 - iyf1, wx = sx1 - ixf1;
                const float* t1 = &tile[lr1 * LSTR + lc1];
                float v00 = t1[0], v01 = t1[1];
                float v10 = t1[LSTR], v11 = t1[LSTR + 1];
                float wx1 = 1.0f - wx, wy1 = 1.0f - wy;
                acc1 += wy1 * (wx1 * v00 + wx * v01) + wy * (wx1 * v10 + wx * v11);
            }
        }
        if (pp) __syncthreads();
        red[0][tid] = acc0;
        red[1][tid] = acc1;
        __syncthreads();
        if (tid < 256) {
            float r0 = red[0][tid] + red[0][tid + 256] + red[0][tid + 512] + red[0][tid + 768];
            float r1 = red[1][tid] + red[1][tid + 256] + red[1][tid + 512] + red[1][tid + 768];
            size_t base = (((size_t)h * BCH + n) * AANG);
            partial[(base + a0) * NN + tid] = r0;
            partial[(base + a1) * NN + tid] = r1;
        }
    }
}

// ---------------- QKV v7: 8 rows/block (384 blocks). Q,V row-major (coalesced
// stores over j); Kt[n][j][i] via two float4 scatter-stores (write-once; the
// 32x-reused attn READS get the coalescing instead). ----
__global__ void qkv_kernel(const float* __restrict__ partial,
                           const float* __restrict__ WqT, const float* __restrict__ bq,
                           const float* __restrict__ WkT, const float* __restrict__ bk,
                           const float* __restrict__ WvT, const float* __restrict__ bv,
                           float* __restrict__ Q, float* __restrict__ Kt,
                           float* __restrict__ V) {
    __shared__ float srow_t[AANG][8];
    int blk = blockIdx.x;  // n*32 + i8
    int n = blk >> 5;
    int i0 = (blk & 31) * 8;
    int tid = threadIdx.x;  // 256
    const size_t HOFF = (size_t)BCH * AANG * NN;
    if (tid < AANG) {
        size_t idx = (((size_t)n) * AANG + tid) * NN + i0;
        float4 p0 = *(const float4*)&partial[idx];
        float4 p1 = *(const float4*)&partial[idx + 4];
        float4 q0 = *(const float4*)&partial[idx + HOFF];
        float4 q1 = *(const float4*)&partial[idx + HOFF + 4];
        srow_t[tid][0] = p0.x + q0.x;
        srow_t[tid][1] = p0.y + q0.y;
        srow_t[tid][2] = p0.z + q0.z;
        srow_t[tid][3] = p0.w + q0.w;
        srow_t[tid][4] = p1.x + q1.x;
        srow_t[tid][5] = p1.y + q1.y;
        srow_t[tid][6] = p1.z + q1.z;
        srow_t[tid][7] = p1.w + q1.w;
    }
    __syncthreads();
    if (tid < AANG) {
        int j = tid;
        float aq[8], ak[8], av[8];
        float bqv = bq[j], bkv = bk[j], bvv = bv[j];
        for (int r = 0; r < 8; ++r) { aq[r] = bqv; ak[r] = bkv; av[r] = bvv; }
#pragma unroll 4
        for (int p = 0; p < AANG; ++p) {
            float wq = WqT[p * AANG + j];
            float wk = WkT[p * AANG + j];
            float wv = WvT[p * AANG + j];
            float4 sv0 = *(const float4*)&srow_t[p][0];
            float4 sv1 = *(const float4*)&srow_t[p][4];
            aq[0] += sv0.x * wq; ak[0] += sv0.x * wk; av[0] += sv0.x * wv;
            aq[1] += sv0.y * wq; ak[1] += sv0.y * wk; av[1] += sv0.y * wv;
            aq[2] += sv0.z * wq; ak[2] += sv0.z * wk; av[2] += sv0.z * wv;
            aq[3] += sv0.w * wq; ak[3] += sv0.w * wk; av[3] += sv0.w * wv;
            aq[4] += sv1.x * wq; ak[4] += sv1.x * wk; av[4] += sv1.x * wv;
            aq[5] += sv1.y * wq; ak[5] += sv1.y * wk; av[5] += sv1.y * wv;
            aq[6] += sv1.z * wq; ak[6] += sv1.z * wk; av[6] += sv1.z * wv;
            aq[7] += sv1.w * wq; ak[7] += sv1.w * wk; av[7] += sv1.w * wv;
        }
        for (int r = 0; r < 8; ++r) {
            size_t qb = ((size_t)(n * NN + i0 + r)) * AANG + j;
            Q[qb] = aq[r];  // coalesced over j
            V[qb] = av[r];  // row-major, coalesced over j (PV reads coalesced)
        }
        size_t kb = ((size_t)(n * AANG + j)) * NN + i0;
        *(float4*)&Kt[kb]     = make_float4(ak[0], ak[1], ak[2], ak[3]);
        *(float4*)&Kt[kb + 4] = make_float4(ak[4], ak[5], ak[6], ak[7]);
    }
}

// ---------------- Attention v7: 8 rows/block; COALESCED global streams
// (Kt lane-k, V lane-j), float4 LDS broadcasts, shfl reductions.
// Per-accumulator order (j,k ascending) identical to all passing versions. ----
__global__ void attn_kernel(const float* __restrict__ Q, const float* __restrict__ Kt,
                            const float* __restrict__ V, float* __restrict__ att_t) {
    __shared__ float qrow[8][AANG];   // 720 B row stride (16B-aligned)
    __shared__ float prob[8][NN];
    __shared__ float wm[8][4], wsm[8][4];
    int blk = blockIdx.x;  // n*32 + i8
    int n = blk >> 5;
    int i0 = (blk & 31) * 8;
    int tid = threadIdx.x;  // 256: key index k
    int wid = tid >> 6;
    if (tid < AANG) {
#pragma unroll
        for (int r = 0; r < 8; ++r)
            qrow[r][tid] = Q[((size_t)(n * NN + i0 + r)) * AANG + tid];
    }
    __syncthreads();
    float d[8];
#pragma unroll
    for (int r = 0; r < 8; ++r) d[r] = 0.0f;
    const float* kcol = Kt + (size_t)n * AANG * NN + tid;  // lane k: coalesced
#pragma unroll 3
    for (int jj = 0; jj < AANG / 4; ++jj) {
        float kv0 = kcol[(size_t)(jj * 4 + 0) * NN];
        float kv1 = kcol[(size_t)(jj * 4 + 1) * NN];
        float kv2 = kcol[(size_t)(jj * 4 + 2) * NN];
        float kv3 = kcol[(size_t)(jj * 4 + 3) * NN];
#pragma unroll
        for (int r = 0; r < 8; ++r) {
            float4 qv = *(const float4*)&qrow[r][jj * 4];
            d[r] += qv.x * kv0;
            d[r] += qv.y * kv1;
            d[r] += qv.z * kv2;
            d[r] += qv.w * kv3;
        }
    }
    const float rs = 0.0745355992f;  // 1/sqrt(180)
    float l[8], m[8], e[8], s[8];
#pragma unroll
    for (int r = 0; r < 8; ++r) { l[r] = d[r] * rs; m[r] = l[r]; }
    for (int off = 32; off > 0; off >>= 1) {
#pragma unroll
        for (int r = 0; r < 8; ++r) m[r] = fmaxf(m[r], __shfl_xor(m[r], off));
    }
    if ((tid & 63) == 0) {
#pragma unroll
        for (int r = 0; r < 8; ++r) wm[r][wid] = m[r];
    }
    __syncthreads();
#pragma unroll
    for (int r = 0; r < 8; ++r) {
        float mx = fmaxf(fmaxf(wm[r][0], wm[r][1]), fmaxf(wm[r][2], wm[r][3]));
        e[r] = expf(l[r] - mx);
        s[r] = e[r];
    }
    for (int off = 32; off > 0; off >>= 1) {
#pragma unroll
        for (int r = 0; r < 8; ++r) s[r] += __shfl_xor(s[r], off);
    }
    if ((tid & 63) == 0) {
#pragma unroll
        for (int r = 0; r < 8; ++r) wsm[r][wid] = s[r];
    }
    __syncthreads();
#pragma unroll
    for (int r = 0; r < 8; ++r) {
        float dn = wsm[r][0] + wsm[r][1] + wsm[r][2] + wsm[r][3];
        prob[r][tid] = e[r] / dn;
    }
    __syncthreads();
    if (tid < AANG) {
        float a[8];
#pragma unroll
        for (int r = 0; r < 8; ++r) a[r] = 0.0f;
        const float* vcol = V + (size_t)n * NN * AANG + tid;  // lane j: coalesced
#pragma unroll 4
        for (int kk = 0; kk < NN / 4; ++kk) {
            float v0 = vcol[(size_t)(kk * 4 + 0) * AANG];
            float v1 = vcol[(size_t)(kk * 4 + 1) * AANG];
            float v2 = vcol[(size_t)(kk * 4 + 2) * AANG];
            float v3 = vcol[(size_t)(kk * 4 + 3) * AANG];
#pragma unroll
            for (int r = 0; r < 8; ++r) {
                float4 p4 = *(const float4*)&prob[r][kk * 4];
                a[r] += p4.x * v0;
                a[r] += p4.y * v1;
                a[r] += p4.z * v2;
                a[r] += p4.w * v3;
            }
        }
        size_t ob = ((size_t)(n * AANG + tid)) * NN + i0;
        *(float4*)&att_t[ob]     = make_float4(a[0], a[1], a[2], a[3]);
        *(float4*)&att_t[ob + 4] = make_float4(a[4], a[5], a[6], a[7]);
    }
}

// ---------------- Ramp filter v2: zero-padded scol, no boundary selects. ----
__global__ void filter_kernel(const float* __restrict__ att_t, float* __restrict__ filt) {
    __shared__ float scol[512];  // [128..383] = data, rest 0
    __shared__ float coef[128];
    int blk = blockIdx.x;  // n*AANG + a
    int tid = threadIdx.x;
    const float* src = &att_t[(size_t)blk * NN];
    scol[tid] = (tid >= 128) ? src[tid - 128] : 0.0f;
    scol[tid + 256] = (tid < 128) ? src[tid + 128] : 0.0f;
    if (tid < 128) {
        float d = (float)(2 * tid + 1);
        coef[tid] = -2.0f / ((float)(M_PI * M_PI) * d * d);
    }
    __syncthreads();
    const float* c = &scol[tid + 128];
    float acc = 0.5f * c[0];
#pragma unroll 4
    for (int m = 0; m < 128; ++m) {
        int d = 2 * m + 1;
        acc += coef[m] * (c[-d] + c[d]);
    }
    filt[(size_t)blk * NN + tid] = acc;
}

// ---------------- Backprojection v3 (R8-exact): block = (n, 4-row group);
// 1024 threads; 36-angle chunks staged cooperatively. ----
#define ACH 36
__global__ __launch_bounds__(1024)
void backproj_kernel(const float* __restrict__ filt, float* __restrict__ out) {
    __shared__ float cols[ACH][NN];
    __shared__ float cs[AANG], sn[AANG];
    int blk = blockIdx.x;  // n*64 + rg
    int n = blk >> 6;
    int rg = blk & 63;
    int tid = threadIdx.x;
    int col = tid & 255;
    int rslot = tid >> 8;
    int r = rg * 4 + rslot;
    if (tid < AANG) {
        float th = (float)((double)tid * (M_PI / 180.0));
        cs[tid] = cosf(th);
        sn[tid] = sinf(th);
    }
    float xr = (float)(r - 128);
    float yr = (float)(col - 128);
    float acc = 0.0f;
    const float* fb = filt + (size_t)n * AANG * NN;
    for (int ch = 0; ch < AANG / ACH; ++ch) {
        __syncthreads();
        for (int idx = tid; idx < ACH * NN; idx += 1024) {
            int q = idx >> 8;
            int cc = idx & 255;
            cols[q][cc] = fb[(size_t)(ch * ACH + q) * NN + cc];
        }
        __syncthreads();
#pragma unroll 4
        for (int q = 0; q < ACH; ++q) {
            int aa = ch * ACH + q;
            float t = yr * cs[aa] - xr * sn[aa] + 128.0f;
            float i0f = floorf(t);
            int i0 = (int)i0f;
            float frac = t - i0f;
            int c0 = iclamp(i0, 0, NN - 1);
            int c1 = iclamp(i0 + 1, 0, NN - 1);
            float val = (1.0f - frac) * cols[q][c0] + frac * cols[q][c1];
            if (t >= 0.0f && t <= 255.0f) acc += val;
        }
    }
    bool inside = (xr * xr + yr * yr) <= 16384.0f;
    out[((size_t)(n * NN + r)) * NN + col] = inside ? acc * (float)(M_PI / 360.0) : 0.0f;
}

extern "C" void kernel_launch(void* const* d_in, const int* in_sizes, int n_in,
                              void* d_out, int out_size, void* d_ws, size_t ws_size,
                              hipStream_t stream) {
    const float* x  = (const float*)d_in[0];
    const float* Wq = (const float*)d_in[1];
    const float* bq = (const float*)d_in[2];
    const float* Wk = (const float*)d_in[3];
    const float* bk = (const float*)d_in[4];
    const float* Wv = (const float*)d_in[5];
    const float* bv = (const float*)d_in[6];
    float* out = (float*)d_out;
    float* ws = (float*)d_ws;

    const size_t SZ = (size_t)BCH * NN * AANG;
    float* P     = ws;           // partial[2][n][a][x]
    float* Q     = P + 2 * SZ;
    float* Kt    = Q + SZ;       // transposed: Kt[n][j][i] (attn reads coalesced)
    float* V     = Kt + SZ;      // row-major (attn PV reads coalesced)
    float* att_t = V + SZ;
    float* WqT   = att_t;        // alias: W-transposes dead before attn writes att_t
    float* WkT   = WqT + AANG * AANG;
    float* WvT   = WkT + AANG * AANG;
    float* filt  = P;            // alias: partials dead after qkv

    radon_kernel<<<BCH * 2 * 30, 1024, 0, stream>>>(x, P, Wq, Wk, Wv, WqT, WkT, WvT);
    qkv_kernel<<<BCH * (NN / 8), 256, 0, stream>>>(P, WqT, bq, WkT, bk, WvT, bv, Q, Kt, V);
    attn_kernel<<<BCH * (NN / 8), 256, 0, stream>>>(Q, Kt, V, att_t);
    filter_kernel<<<BCH * AANG, NN, 0, stream>>>(att_t, filt);
    backproj_kernel<<<BCH * (NN / 4), 1024, 0, stream>>>(filt, out);
}

// Round 14
// 433.989 us; speedup vs baseline: 1.4544x; 1.0185x over previous
//
#include <hip/hip_runtime.h>

#define AANG 180
#define NN 256
#define BCH 12

#ifndef M_PI
#define M_PI 3.14159265358979323846
#endif

__device__ __forceinline__ int iclamp(int v, int lo, int hi) {
    return v < lo ? lo : (v > hi ? hi : v);
}

// ---------------- Radon v11: R8-exact per-sample math, TRIPLE-angle ILP
// (2 passes x 3 angles), wtrans prologue. Sample set, per-sample FP
// expressions, and all accumulation orders bit-identical to R13.
#define LSTR 259
#define LROWSMAX 130

__global__ __launch_bounds__(1024, 1)
void radon_kernel(const float* __restrict__ x, float* __restrict__ partial,
                  const float* __restrict__ Wq, const float* __restrict__ Wk,
                  const float* __restrict__ Wv, float* __restrict__ WqT,
                  float* __restrict__ WkT, float* __restrict__ WvT) {
    __shared__ float tile[LROWSMAX * LSTR];  // 134,680 B
    __shared__ float red[3][1024];           // + 12 KB  (146.9 KB total)
    int blk = blockIdx.x;        // ((n*2)+h)*30 + g
    int tid = threadIdx.x;

    // --- wtrans prologue: 720 blocks x 45 elements = 32400 (exact) ---
    if (tid < 45) {
        int idx = blk * 45 + tid;
        int p = idx / AANG;
        int j = idx - p * AANG;
        int src = j * AANG + p;
        WqT[idx] = Wq[src];
        WkT[idx] = Wk[src];
        WvT[idx] = Wv[src];
    }

    int g = blk % 30;
    int t = blk / 30;
    int h = t & 1;
    int n = t >> 1;
    int lx = tid & 255;
    int qid = tid >> 8;
    int R0 = h ? 127 : -1;
    int nrows = h ? 130 : 129;
    unsigned lrmax = h ? 128u : 127u;  // valid lr in [0, lrmax]
    const float* img = x + (size_t)n * NN * NN;

    for (int rr = qid; rr < nrows; rr += 4) {
        int gr = R0 + rr;
        bool rok = (gr >= 0) && (gr < NN);
        const float* row = img + gr * NN;
        int gc = lx - 1;
        tile[rr * LSTR + lx] = (rok && gc >= 0) ? row[gc] : 0.0f;
        if (lx < 3) {
            int gc2 = 255 + lx;
            tile[rr * LSTR + 256 + lx] = (rok && gc2 < NN) ? row[gc2] : 0.0f;
        }
    }
    __syncthreads();

    float fx = (float)lx;
    int ubase = qid * 64;

    for (int pp = 0; pp < 2; ++pp) {
        int a0 = g + (3 * pp + 0) * 30;
        int a1 = g + (3 * pp + 1) * 30;
        int a2 = g + (3 * pp + 2) * 30;
        float th0 = (float)((double)a0 * (M_PI / 180.0));
        float th1 = (float)((double)a1 * (M_PI / 180.0));
        float th2 = (float)((double)a2 * (M_PI / 180.0));
        float c0 = cosf(th0), s0 = sinf(th0);
        float c1 = cosf(th1), s1 = sinf(th1);
        float c2 = cosf(th2), s2 = sinf(th2);
        float kx0 = -128.0f * (c0 + s0 - 1.0f), ky0 = -128.0f * (c0 - s0 - 1.0f);
        float kx1 = -128.0f * (c1 + s1 - 1.0f), ky1 = -128.0f * (c1 - s1 - 1.0f);
        float kx2 = -128.0f * (c2 + s2 - 1.0f), ky2 = -128.0f * (c2 - s2 - 1.0f);
        // exact constants (no folding of R0/+1 — FP-rounding sensitive)
        float xcon0 = c0 * fx + kx0;   // sx = fma(s, fy, xcon)
        float dcon0 = -s0 * fx + ky0;  // sy = fma(c, fy, dcon)
        float xcon1 = c1 * fx + kx1;
        float dcon1 = -s1 * fx + ky1;
        float xcon2 = c2 * fx + kx2;
        float dcon2 = -s2 * fx + ky2;
        float acc0 = 0.0f, acc1 = 0.0f, acc2 = 0.0f;
#pragma unroll 2
        for (int i = 0; i < 64; ++i) {
            float fy = (float)(ubase + i);
            float sy0 = __builtin_fmaf(c0, fy, dcon0);
            float sx0 = __builtin_fmaf(s0, fy, xcon0);
            float sy1 = __builtin_fmaf(c1, fy, dcon1);
            float sx1 = __builtin_fmaf(s1, fy, xcon1);
            float sy2 = __builtin_fmaf(c2, fy, dcon2);
            float sx2 = __builtin_fmaf(s2, fy, xcon2);
            float iyf0 = floorf(sy0), ixf0 = floorf(sx0);
            float iyf1 = floorf(sy1), ixf1 = floorf(sx1);
            float iyf2 = floorf(sy2), ixf2 = floorf(sx2);
            int lr0 = (int)iyf0 - R0, lc0 = (int)ixf0 + 1;
            int lr1 = (int)iyf1 - R0, lc1 = (int)ixf1 + 1;
            int lr2 = (int)iyf2 - R0, lc2 = (int)ixf2 + 1;
            if ((unsigned)lr0 <= lrmax && (unsigned)lc0 <= 256u) {
                float wy = sy0 - iyf0, wx = sx0 - ixf0;
                const float* t0 = &tile[lr0 * LSTR + lc0];
                float v00 = t0[0], v01 = t0[1];
                float v10 = t0[LSTR], v11 = t0[LSTR + 1];
                float wx1 = 1.0f - wx, wy1 = 1.0f - wy;
                acc0 += wy1 * (wx1 * v00 + wx * v01) + wy * (wx1 * v10 + wx * v11);
            }
            if ((unsigned)lr1 <= lrmax && (unsigned)lc1 <= 256u) {
                float wy = sy1 - iyf1, wx = sx1 - ixf1;
                const float* t1 = &tile[lr1 * LSTR + lc1];
                float v00 = t1[0], v01 = t1[1];
                float v10 = t1[LSTR], v11 = t1[LSTR + 1];
                float wx1 = 1.0f - wx, wy1 = 1.0f - wy;
                acc1 += wy1 * (wx1 * v00 + wx * v01) + wy * (wx1 * v10 + wx * v11);
            }
            if ((unsigned)lr2 <= lrmax && (unsigned)lc2 <= 256u) {
                float wy = sy2 - iyf2, wx = sx2 - ixf2;
                const float* t2 = &tile[lr2 * LSTR + lc2];
                float v00 = t2[0], v01 = t2[1];
                float v10 = t2[LSTR], v11 = t2[LSTR + 1];
                float wx1 = 1.0f - wx, wy1 = 1.0f - wy;
                acc2 += wy1 * (wx1 * v00 + wx * v01) + wy * (wx1 * v10 + wx * v11);
            }
        }
        if (pp) __syncthreads();
        red[0][tid] = acc0;
        red[1][tid] = acc1;
        red[2][tid] = acc2;
        __syncthreads();
        if (tid < 256) {
            float r0 = red[0][tid] + red[0][tid + 256] + red[0][tid + 512] + red[0][tid + 768];
            float r1 = red[1][tid] + red[1][tid + 256] + red[1][tid + 512] + red[1][tid + 768];
            float r2 = red[2][tid] + red[2][tid + 256] + red[2][tid + 512] + red[2][tid + 768];
            size_t base = (((size_t)h * BCH + n) * AANG);
            partial[(base + a0) * NN + tid] = r0;
            partial[(base + a1) * NN + tid] = r1;
            partial[(base + a2) * NN + tid] = r2;
        }
    }
}

// ---------------- QKV v7 (R13): 8 rows/block. Q,V row-major; Kt scatter-stores.
__global__ void qkv_kernel(const float* __restrict__ partial,
                           const float* __restrict__ WqT, const float* __restrict__ bq,
                           const float* __restrict__ WkT, const float* __restrict__ bk,
                           const float* __restrict__ WvT, const float* __restrict__ bv,
                           float* __restrict__ Q, float* __restrict__ Kt,
                           float* __restrict__ V) {
    __shared__ float srow_t[AANG][8];
    int blk = blockIdx.x;  // n*32 + i8
    int n = blk >> 5;
    int i0 = (blk & 31) * 8;
    int tid = threadIdx.x;  // 256
    const size_t HOFF = (size_t)BCH * AANG * NN;
    if (tid < AANG) {
        size_t idx = (((size_t)n) * AANG + tid) * NN + i0;
        float4 p0 = *(const float4*)&partial[idx];
        float4 p1 = *(const float4*)&partial[idx + 4];
        float4 q0 = *(const float4*)&partial[idx + HOFF];
        float4 q1 = *(const float4*)&partial[idx + HOFF + 4];
        srow_t[tid][0] = p0.x + q0.x;
        srow_t[tid][1] = p0.y + q0.y;
        srow_t[tid][2] = p0.z + q0.z;
        srow_t[tid][3] = p0.w + q0.w;
        srow_t[tid][4] = p1.x + q1.x;
        srow_t[tid][5] = p1.y + q1.y;
        srow_t[tid][6] = p1.z + q1.z;
        srow_t[tid][7] = p1.w + q1.w;
    }
    __syncthreads();
    if (tid < AANG) {
        int j = tid;
        float aq[8], ak[8], av[8];
        float bqv = bq[j], bkv = bk[j], bvv = bv[j];
        for (int r = 0; r < 8; ++r) { aq[r] = bqv; ak[r] = bkv; av[r] = bvv; }
#pragma unroll 4
        for (int p = 0; p < AANG; ++p) {
            float wq = WqT[p * AANG + j];
            float wk = WkT[p * AANG + j];
            float wv = WvT[p * AANG + j];
            float4 sv0 = *(const float4*)&srow_t[p][0];
            float4 sv1 = *(const float4*)&srow_t[p][4];
            aq[0] += sv0.x * wq; ak[0] += sv0.x * wk; av[0] += sv0.x * wv;
            aq[1] += sv0.y * wq; ak[1] += sv0.y * wk; av[1] += sv0.y * wv;
            aq[2] += sv0.z * wq; ak[2] += sv0.z * wk; av[2] += sv0.z * wv;
            aq[3] += sv0.w * wq; ak[3] += sv0.w * wk; av[3] += sv0.w * wv;
            aq[4] += sv1.x * wq; ak[4] += sv1.x * wk; av[4] += sv1.x * wv;
            aq[5] += sv1.y * wq; ak[5] += sv1.y * wk; av[5] += sv1.y * wv;
            aq[6] += sv1.z * wq; ak[6] += sv1.z * wk; av[6] += sv1.z * wv;
            aq[7] += sv1.w * wq; ak[7] += sv1.w * wk; av[7] += sv1.w * wv;
        }
        for (int r = 0; r < 8; ++r) {
            size_t qb = ((size_t)(n * NN + i0 + r)) * AANG + j;
            Q[qb] = aq[r];  // coalesced over j
            V[qb] = av[r];  // row-major, coalesced over j (PV reads coalesced)
        }
        size_t kb = ((size_t)(n * AANG + j)) * NN + i0;
        *(float4*)&Kt[kb]     = make_float4(ak[0], ak[1], ak[2], ak[3]);
        *(float4*)&Kt[kb + 4] = make_float4(ak[4], ak[5], ak[6], ak[7]);
    }
}

// ---------------- Attention v7 (R13): 8 rows/block; coalesced Kt/V streams. ----
__global__ void attn_kernel(const float* __restrict__ Q, const float* __restrict__ Kt,
                            const float* __restrict__ V, float* __restrict__ att_t) {
    __shared__ float qrow[8][AANG];
    __shared__ float prob[8][NN];
    __shared__ float wm[8][4], wsm[8][4];
    int blk = blockIdx.x;  // n*32 + i8
    int n = blk >> 5;
    int i0 = (blk & 31) * 8;
    int tid = threadIdx.x;  // 256: key index k
    int wid = tid >> 6;
    if (tid < AANG) {
#pragma unroll
        for (int r = 0; r < 8; ++r)
            qrow[r][tid] = Q[((size_t)(n * NN + i0 + r)) * AANG + tid];
    }
    __syncthreads();
    float d[8];
#pragma unroll
    for (int r = 0; r < 8; ++r) d[r] = 0.0f;
    const float* kcol = Kt + (size_t)n * AANG * NN + tid;  // lane k: coalesced
#pragma unroll 3
    for (int jj = 0; jj < AANG / 4; ++jj) {
        float kv0 = kcol[(size_t)(jj * 4 + 0) * NN];
        float kv1 = kcol[(size_t)(jj * 4 + 1) * NN];
        float kv2 = kcol[(size_t)(jj * 4 + 2) * NN];
        float kv3 = kcol[(size_t)(jj * 4 + 3) * NN];
#pragma unroll
        for (int r = 0; r < 8; ++r) {
            float4 qv = *(const float4*)&qrow[r][jj * 4];
            d[r] += qv.x * kv0;
            d[r] += qv.y * kv1;
            d[r] += qv.z * kv2;
            d[r] += qv.w * kv3;
        }
    }
    const float rs = 0.0745355992f;  // 1/sqrt(180)
    float l[8], m[8], e[8], s[8];
#pragma unroll
    for (int r = 0; r < 8; ++r) { l[r] = d[r] * rs; m[r] = l[r]; }
    for (int off = 32; off > 0; off >>= 1) {
#pragma unroll
        for (int r = 0; r < 8; ++r) m[r] = fmaxf(m[r], __shfl_xor(m[r], off));
    }
    if ((tid & 63) == 0) {
#pragma unroll
        for (int r = 0; r < 8; ++r) wm[r][wid] = m[r];
    }
    __syncthreads();
#pragma unroll
    for (int r = 0; r < 8; ++r) {
        float mx = fmaxf(fmaxf(wm[r][0], wm[r][1]), fmaxf(wm[r][2], wm[r][3]));
        e[r] = expf(l[r] - mx);
        s[r] = e[r];
    }
    for (int off = 32; off > 0; off >>= 1) {
#pragma unroll
        for (int r = 0; r < 8; ++r) s[r] += __shfl_xor(s[r], off);
    }
    if ((tid & 63) == 0) {
#pragma unroll
        for (int r = 0; r < 8; ++r) wsm[r][wid] = s[r];
    }
    __syncthreads();
#pragma unroll
    for (int r = 0; r < 8; ++r) {
        float dn = wsm[r][0] + wsm[r][1] + wsm[r][2] + wsm[r][3];
        prob[r][tid] = e[r] / dn;
    }
    __syncthreads();
    if (tid < AANG) {
        float a[8];
#pragma unroll
        for (int r = 0; r < 8; ++r) a[r] = 0.0f;
        const float* vcol = V + (size_t)n * NN * AANG + tid;  // lane j: coalesced
#pragma unroll 4
        for (int kk = 0; kk < NN / 4; ++kk) {
            float v0 = vcol[(size_t)(kk * 4 + 0) * AANG];
            float v1 = vcol[(size_t)(kk * 4 + 1) * AANG];
            float v2 = vcol[(size_t)(kk * 4 + 2) * AANG];
            float v3 = vcol[(size_t)(kk * 4 + 3) * AANG];
#pragma unroll
            for (int r = 0; r < 8; ++r) {
                float4 p4 = *(const float4*)&prob[r][kk * 4];
                a[r] += p4.x * v0;
                a[r] += p4.y * v1;
                a[r] += p4.z * v2;
                a[r] += p4.w * v3;
            }
        }
        size_t ob = ((size_t)(n * AANG + tid)) * NN + i0;
        *(float4*)&att_t[ob]     = make_float4(a[0], a[1], a[2], a[3]);
        *(float4*)&att_t[ob + 4] = make_float4(a[4], a[5], a[6], a[7]);
    }
}

// ---------------- Ramp filter v2: zero-padded scol, no boundary selects. ----
__global__ void filter_kernel(const float* __restrict__ att_t, float* __restrict__ filt) {
    __shared__ float scol[512];  // [128..383] = data, rest 0
    __shared__ float coef[128];
    int blk = blockIdx.x;  // n*AANG + a
    int tid = threadIdx.x;
    const float* src = &att_t[(size_t)blk * NN];
    scol[tid] = (tid >= 128) ? src[tid - 128] : 0.0f;
    scol[tid + 256] = (tid < 128) ? src[tid + 128] : 0.0f;
    if (tid < 128) {
        float d = (float)(2 * tid + 1);
        coef[tid] = -2.0f / ((float)(M_PI * M_PI) * d * d);
    }
    __syncthreads();
    const float* c = &scol[tid + 128];
    float acc = 0.5f * c[0];
#pragma unroll 4
    for (int m = 0; m < 128; ++m) {
        int d = 2 * m + 1;
        acc += coef[m] * (c[-d] + c[d]);
    }
    filt[(size_t)blk * NN + tid] = acc;
}

// ---------------- Backprojection v3 (R8-exact): block = (n, 4-row group). ----
#define ACH 36
__global__ __launch_bounds__(1024)
void backproj_kernel(const float* __restrict__ filt, float* __restrict__ out) {
    __shared__ float cols[ACH][NN];
    __shared__ float cs[AANG], sn[AANG];
    int blk = blockIdx.x;  // n*64 + rg
    int n = blk >> 6;
    int rg = blk & 63;
    int tid = threadIdx.x;
    int col = tid & 255;
    int rslot = tid >> 8;
    int r = rg * 4 + rslot;
    if (tid < AANG) {
        float th = (float)((double)tid * (M_PI / 180.0));
        cs[tid] = cosf(th);
        sn[tid] = sinf(th);
    }
    float xr = (float)(r - 128);
    float yr = (float)(col - 128);
    float acc = 0.0f;
    const float* fb = filt + (size_t)n * AANG * NN;
    for (int ch = 0; ch < AANG / ACH; ++ch) {
        __syncthreads();
        for (int idx = tid; idx < ACH * NN; idx += 1024) {
            int q = idx >> 8;
            int cc = idx & 255;
            cols[q][cc] = fb[(size_t)(ch * ACH + q) * NN + cc];
        }
        __syncthreads();
#pragma unroll 4
        for (int q = 0; q < ACH; ++q) {
            int aa = ch * ACH + q;
            float t = yr * cs[aa] - xr * sn[aa] + 128.0f;
            float i0f = floorf(t);
            int i0 = (int)i0f;
            float frac = t - i0f;
            int c0 = iclamp(i0, 0, NN - 1);
            int c1 = iclamp(i0 + 1, 0, NN - 1);
            float val = (1.0f - frac) * cols[q][c0] + frac * cols[q][c1];
            if (t >= 0.0f && t <= 255.0f) acc += val;
        }
    }
    bool inside = (xr * xr + yr * yr) <= 16384.0f;
    out[((size_t)(n * NN + r)) * NN + col] = inside ? acc * (float)(M_PI / 360.0) : 0.0f;
}

extern "C" void kernel_launch(void* const* d_in, const int* in_sizes, int n_in,
                              void* d_out, int out_size, void* d_ws, size_t ws_size,
                              hipStream_t stream) {
    const float* x  = (const float*)d_in[0];
    const float* Wq = (const float*)d_in[1];
    const float* bq = (const float*)d_in[2];
    const float* Wk = (const float*)d_in[3];
    const float* bk = (const float*)d_in[4];
    const float* Wv = (const float*)d_in[5];
    const float* bv = (const float*)d_in[6];
    float* out = (float*)d_out;
    float* ws = (float*)d_ws;

    const size_t SZ = (size_t)BCH * NN * AANG;
    float* P     = ws;           // partial[2][n][a][x]
    float* Q     = P + 2 * SZ;
    float* Kt    = Q + SZ;       // transposed: Kt[n][j][i] (attn reads coalesced)
    float* V     = Kt + SZ;      // row-major (attn PV reads coalesced)
    float* att_t = V + SZ;
    float* WqT   = att_t;        // alias: W-transposes dead before attn writes att_t
    float* WkT   = WqT + AANG * AANG;
    float* WvT   = WkT + AANG * AANG;
    float* filt  = P;            // alias: partials dead after qkv

    radon_kernel<<<BCH * 2 * 30, 1024, 0, stream>>>(x, P, Wq, Wk, Wv, WqT, WkT, WvT);
    qkv_kernel<<<BCH * (NN / 8), 256, 0, stream>>>(P, WqT, bq, WkT, bk, WvT, bv, Q, Kt, V);
    attn_kernel<<<BCH * (NN / 8), 256, 0, stream>>>(Q, Kt, V, att_t);
    filter_kernel<<<BCH * AANG, NN, 0, stream>>>(att_t, filt);
    backproj_kernel<<<BCH * (NN / 4), 1024, 0, stream>>>(filt, out);
}

// Round 15
// 426.846 us; speedup vs baseline: 1.4787x; 1.0167x over previous
//
#include <hip/hip_runtime.h>

#define AANG 180
#define NN 256
#define BCH 12

#ifndef M_PI
#define M_PI 3.14159265358979323846
#endif

__device__ __forceinline__ int iclamp(int v, int lo, int hi) {
    return v < lo ? lo : (v > hi ? hi : v);
}

// ---------------- Radon v12: R8-exact per-sample math, SIX-angle ILP
// (1 pass x 6 angles), wtrans prologue. Sample set, per-sample FP
// expressions, and all accumulation orders bit-identical to R14.
// LDS: 134,680 + 24,576 = 159,256 B (fits 160 KiB; 1 block/CU as before).
#define LSTR 259
#define LROWSMAX 130

__global__ __launch_bounds__(1024, 1)
void radon_kernel(const float* __restrict__ x, float* __restrict__ partial,
                  const float* __restrict__ Wq, const float* __restrict__ Wk,
                  const float* __restrict__ Wv, float* __restrict__ WqT,
                  float* __restrict__ WkT, float* __restrict__ WvT) {
    __shared__ float tile[LROWSMAX * LSTR];  // 134,680 B
    __shared__ float red[6][1024];           // + 24 KB
    int blk = blockIdx.x;        // ((n*2)+h)*30 + g
    int tid = threadIdx.x;

    // --- wtrans prologue: 720 blocks x 45 elements = 32400 (exact) ---
    if (tid < 45) {
        int idx = blk * 45 + tid;
        int p = idx / AANG;
        int j = idx - p * AANG;
        int src = j * AANG + p;
        WqT[idx] = Wq[src];
        WkT[idx] = Wk[src];
        WvT[idx] = Wv[src];
    }

    int g = blk % 30;
    int t = blk / 30;
    int h = t & 1;
    int n = t >> 1;
    int lx = tid & 255;
    int qid = tid >> 8;
    int R0 = h ? 127 : -1;
    int nrows = h ? 130 : 129;
    unsigned lrmax = h ? 128u : 127u;  // valid lr in [0, lrmax]
    const float* img = x + (size_t)n * NN * NN;

    for (int rr = qid; rr < nrows; rr += 4) {
        int gr = R0 + rr;
        bool rok = (gr >= 0) && (gr < NN);
        const float* row = img + gr * NN;
        int gc = lx - 1;
        tile[rr * LSTR + lx] = (rok && gc >= 0) ? row[gc] : 0.0f;
        if (lx < 3) {
            int gc2 = 255 + lx;
            tile[rr * LSTR + 256 + lx] = (rok && gc2 < NN) ? row[gc2] : 0.0f;
        }
    }
    __syncthreads();

    float fx = (float)lx;
    int ubase = qid * 64;

    // 6 angles a = g + k*30, k=0..5 — all in one pass (6 independent chains).
    float c[6], s[6], xcon[6], dcon[6], acc[6];
#pragma unroll
    for (int k = 0; k < 6; ++k) {
        int a = g + k * 30;
        float th = (float)((double)a * (M_PI / 180.0));
        c[k] = cosf(th);
        s[k] = sinf(th);
        float kx = -128.0f * (c[k] + s[k] - 1.0f);
        float ky = -128.0f * (c[k] - s[k] - 1.0f);
        xcon[k] = c[k] * fx + kx;    // sx = fma(s, fy, xcon)
        dcon[k] = -s[k] * fx + ky;   // sy = fma(c, fy, dcon)
        acc[k] = 0.0f;
    }
    for (int i = 0; i < 64; ++i) {
        float fy = (float)(ubase + i);
#pragma unroll
        for (int k = 0; k < 6; ++k) {
            float sy = __builtin_fmaf(c[k], fy, dcon[k]);
            float sx = __builtin_fmaf(s[k], fy, xcon[k]);
            float iyf = floorf(sy), ixf = floorf(sx);
            int lr = (int)iyf - R0, lc = (int)ixf + 1;
            if ((unsigned)lr <= lrmax && (unsigned)lc <= 256u) {
                float wy = sy - iyf, wx = sx - ixf;
                const float* tp = &tile[lr * LSTR + lc];
                float v00 = tp[0], v01 = tp[1];
                float v10 = tp[LSTR], v11 = tp[LSTR + 1];
                float wx1 = 1.0f - wx, wy1 = 1.0f - wy;
                acc[k] += wy1 * (wx1 * v00 + wx * v01) + wy * (wx1 * v10 + wx * v11);
            }
        }
    }
#pragma unroll
    for (int k = 0; k < 6; ++k) red[k][tid] = acc[k];
    __syncthreads();
    if (tid < 256) {
        size_t base = (((size_t)h * BCH + n) * AANG);
#pragma unroll
        for (int k = 0; k < 6; ++k) {
            float r = red[k][tid] + red[k][tid + 256] + red[k][tid + 512] + red[k][tid + 768];
            partial[(base + (g + k * 30)) * NN + tid] = r;
        }
    }
}

// ---------------- QKV v7 (R13): 8 rows/block. Q,V row-major; Kt scatter-stores.
__global__ void qkv_kernel(const float* __restrict__ partial,
                           const float* __restrict__ WqT, const float* __restrict__ bq,
                           const float* __restrict__ WkT, const float* __restrict__ bk,
                           const float* __restrict__ WvT, const float* __restrict__ bv,
                           float* __restrict__ Q, float* __restrict__ Kt,
                           float* __restrict__ V) {
    __shared__ float srow_t[AANG][8];
    int blk = blockIdx.x;  // n*32 + i8
    int n = blk >> 5;
    int i0 = (blk & 31) * 8;
    int tid = threadIdx.x;  // 256
    const size_t HOFF = (size_t)BCH * AANG * NN;
    if (tid < AANG) {
        size_t idx = (((size_t)n) * AANG + tid) * NN + i0;
        float4 p0 = *(const float4*)&partial[idx];
        float4 p1 = *(const float4*)&partial[idx + 4];
        float4 q0 = *(const float4*)&partial[idx + HOFF];
        float4 q1 = *(const float4*)&partial[idx + HOFF + 4];
        srow_t[tid][0] = p0.x + q0.x;
        srow_t[tid][1] = p0.y + q0.y;
        srow_t[tid][2] = p0.z + q0.z;
        srow_t[tid][3] = p0.w + q0.w;
        srow_t[tid][4] = p1.x + q1.x;
        srow_t[tid][5] = p1.y + q1.y;
        srow_t[tid][6] = p1.z + q1.z;
        srow_t[tid][7] = p1.w + q1.w;
    }
    __syncthreads();
    if (tid < AANG) {
        int j = tid;
        float aq[8], ak[8], av[8];
        float bqv = bq[j], bkv = bk[j], bvv = bv[j];
        for (int r = 0; r < 8; ++r) { aq[r] = bqv; ak[r] = bkv; av[r] = bvv; }
#pragma unroll 4
        for (int p = 0; p < AANG; ++p) {
            float wq = WqT[p * AANG + j];
            float wk = WkT[p * AANG + j];
            float wv = WvT[p * AANG + j];
            float4 sv0 = *(const float4*)&srow_t[p][0];
            float4 sv1 = *(const float4*)&srow_t[p][4];
            aq[0] += sv0.x * wq; ak[0] += sv0.x * wk; av[0] += sv0.x * wv;
            aq[1] += sv0.y * wq; ak[1] += sv0.y * wk; av[1] += sv0.y * wv;
            aq[2] += sv0.z * wq; ak[2] += sv0.z * wk; av[2] += sv0.z * wv;
            aq[3] += sv0.w * wq; ak[3] += sv0.w * wk; av[3] += sv0.w * wv;
            aq[4] += sv1.x * wq; ak[4] += sv1.x * wk; av[4] += sv1.x * wv;
            aq[5] += sv1.y * wq; ak[5] += sv1.y * wk; av[5] += sv1.y * wv;
            aq[6] += sv1.z * wq; ak[6] += sv1.z * wk; av[6] += sv1.z * wv;
            aq[7] += sv1.w * wq; ak[7] += sv1.w * wk; av[7] += sv1.w * wv;
        }
        for (int r = 0; r < 8; ++r) {
            size_t qb = ((size_t)(n * NN + i0 + r)) * AANG + j;
            Q[qb] = aq[r];  // coalesced over j
            V[qb] = av[r];  // row-major, coalesced over j (PV reads coalesced)
        }
        size_t kb = ((size_t)(n * AANG + j)) * NN + i0;
        *(float4*)&Kt[kb]     = make_float4(ak[0], ak[1], ak[2], ak[3]);
        *(float4*)&Kt[kb + 4] = make_float4(ak[4], ak[5], ak[6], ak[7]);
    }
}

// ---------------- Attention v7 (R13): 8 rows/block; coalesced Kt/V streams. ----
__global__ void attn_kernel(const float* __restrict__ Q, const float* __restrict__ Kt,
                            const float* __restrict__ V, float* __restrict__ att_t) {
    __shared__ float qrow[8][AANG];
    __shared__ float prob[8][NN];
    __shared__ float wm[8][4], wsm[8][4];
    int blk = blockIdx.x;  // n*32 + i8
    int n = blk >> 5;
    int i0 = (blk & 31) * 8;
    int tid = threadIdx.x;  // 256: key index k
    int wid = tid >> 6;
    if (tid < AANG) {
#pragma unroll
        for (int r = 0; r < 8; ++r)
            qrow[r][tid] = Q[((size_t)(n * NN + i0 + r)) * AANG + tid];
    }
    __syncthreads();
    float d[8];
#pragma unroll
    for (int r = 0; r < 8; ++r) d[r] = 0.0f;
    const float* kcol = Kt + (size_t)n * AANG * NN + tid;  // lane k: coalesced
#pragma unroll 3
    for (int jj = 0; jj < AANG / 4; ++jj) {
        float kv0 = kcol[(size_t)(jj * 4 + 0) * NN];
        float kv1 = kcol[(size_t)(jj * 4 + 1) * NN];
        float kv2 = kcol[(size_t)(jj * 4 + 2) * NN];
        float kv3 = kcol[(size_t)(jj * 4 + 3) * NN];
#pragma unroll
        for (int r = 0; r < 8; ++r) {
            float4 qv = *(const float4*)&qrow[r][jj * 4];
            d[r] += qv.x * kv0;
            d[r] += qv.y * kv1;
            d[r] += qv.z * kv2;
            d[r] += qv.w * kv3;
        }
    }
    const float rs = 0.0745355992f;  // 1/sqrt(180)
    float l[8], m[8], e[8], s[8];
#pragma unroll
    for (int r = 0; r < 8; ++r) { l[r] = d[r] * rs; m[r] = l[r]; }
    for (int off = 32; off > 0; off >>= 1) {
#pragma unroll
        for (int r = 0; r < 8; ++r) m[r] = fmaxf(m[r], __shfl_xor(m[r], off));
    }
    if ((tid & 63) == 0) {
#pragma unroll
        for (int r = 0; r < 8; ++r) wm[r][wid] = m[r];
    }
    __syncthreads();
#pragma unroll
    for (int r = 0; r < 8; ++r) {
        float mx = fmaxf(fmaxf(wm[r][0], wm[r][1]), fmaxf(wm[r][2], wm[r][3]));
        e[r] = expf(l[r] - mx);
        s[r] = e[r];
    }
    for (int off = 32; off > 0; off >>= 1) {
#pragma unroll
        for (int r = 0; r < 8; ++r) s[r] += __shfl_xor(s[r], off);
    }
    if ((tid & 63) == 0) {
#pragma unroll
        for (int r = 0; r < 8; ++r) wsm[r][wid] = s[r];
    }
    __syncthreads();
#pragma unroll
    for (int r = 0; r < 8; ++r) {
        float dn = wsm[r][0] + wsm[r][1] + wsm[r][2] + wsm[r][3];
        prob[r][tid] = e[r] / dn;
    }
    __syncthreads();
    if (tid < AANG) {
        float a[8];
#pragma unroll
        for (int r = 0; r < 8; ++r) a[r] = 0.0f;
        const float* vcol = V + (size_t)n * NN * AANG + tid;  // lane j: coalesced
#pragma unroll 4
        for (int kk = 0; kk < NN / 4; ++kk) {
            float v0 = vcol[(size_t)(kk * 4 + 0) * AANG];
            float v1 = vcol[(size_t)(kk * 4 + 1) * AANG];
            float v2 = vcol[(size_t)(kk * 4 + 2) * AANG];
            float v3 = vcol[(size_t)(kk * 4 + 3) * AANG];
#pragma unroll
            for (int r = 0; r < 8; ++r) {
                float4 p4 = *(const float4*)&prob[r][kk * 4];
                a[r] += p4.x * v0;
                a[r] += p4.y * v1;
                a[r] += p4.z * v2;
                a[r] += p4.w * v3;
            }
        }
        size_t ob = ((size_t)(n * AANG + tid)) * NN + i0;
        *(float4*)&att_t[ob]     = make_float4(a[0], a[1], a[2], a[3]);
        *(float4*)&att_t[ob + 4] = make_float4(a[4], a[5], a[6], a[7]);
    }
}

// ---------------- Ramp filter v2: zero-padded scol, no boundary selects. ----
__global__ void filter_kernel(const float* __restrict__ att_t, float* __restrict__ filt) {
    __shared__ float scol[512];  // [128..383] = data, rest 0
    __shared__ float coef[128];
    int blk = blockIdx.x;  // n*AANG + a
    int tid = threadIdx.x;
    const float* src = &att_t[(size_t)blk * NN];
    scol[tid] = (tid >= 128) ? src[tid - 128] : 0.0f;
    scol[tid + 256] = (tid < 128) ? src[tid + 128] : 0.0f;
    if (tid < 128) {
        float d = (float)(2 * tid + 1);
        coef[tid] = -2.0f / ((float)(M_PI * M_PI) * d * d);
    }
    __syncthreads();
    const float* c = &scol[tid + 128];
    float acc = 0.5f * c[0];
#pragma unroll 4
    for (int m = 0; m < 128; ++m) {
        int d = 2 * m + 1;
        acc += coef[m] * (c[-d] + c[d]);
    }
    filt[(size_t)blk * NN + tid] = acc;
}

// ---------------- Backprojection v3 (R8-exact): block = (n, 4-row group). ----
#define ACH 36
__global__ __launch_bounds__(1024)
void backproj_kernel(const float* __restrict__ filt, float* __restrict__ out) {
    __shared__ float cols[ACH][NN];
    __shared__ float cs[AANG], sn[AANG];
    int blk = blockIdx.x;  // n*64 + rg
    int n = blk >> 6;
    int rg = blk & 63;
    int tid = threadIdx.x;
    int col = tid & 255;
    int rslot = tid >> 8;
    int r = rg * 4 + rslot;
    if (tid < AANG) {
        float th = (float)((double)tid * (M_PI / 180.0));
        cs[tid] = cosf(th);
        sn[tid] = sinf(th);
    }
    float xr = (float)(r - 128);
    float yr = (float)(col - 128);
    float acc = 0.0f;
    const float* fb = filt + (size_t)n * AANG * NN;
    for (int ch = 0; ch < AANG / ACH; ++ch) {
        __syncthreads();
        for (int idx = tid; idx < ACH * NN; idx += 1024) {
            int q = idx >> 8;
            int cc = idx & 255;
            cols[q][cc] = fb[(size_t)(ch * ACH + q) * NN + cc];
        }
        __syncthreads();
#pragma unroll 4
        for (int q = 0; q < ACH; ++q) {
            int aa = ch * ACH + q;
            float t = yr * cs[aa] - xr * sn[aa] + 128.0f;
            float i0f = floorf(t);
            int i0 = (int)i0f;
            float frac = t - i0f;
            int c0 = iclamp(i0, 0, NN - 1);
            int c1 = iclamp(i0 + 1, 0, NN - 1);
            float val = (1.0f - frac) * cols[q][c0] + frac * cols[q][c1];
            if (t >= 0.0f && t <= 255.0f) acc += val;
        }
    }
    bool inside = (xr * xr + yr * yr) <= 16384.0f;
    out[((size_t)(n * NN + r)) * NN + col] = inside ? acc * (float)(M_PI / 360.0) : 0.0f;
}

extern "C" void kernel_launch(void* const* d_in, const int* in_sizes, int n_in,
                              void* d_out, int out_size, void* d_ws, size_t ws_size,
                              hipStream_t stream) {
    const float* x  = (const float*)d_in[0];
    const float* Wq = (const float*)d_in[1];
    const float* bq = (const float*)d_in[2];
    const float* Wk = (const float*)d_in[3];
    const float* bk = (const float*)d_in[4];
    const float* Wv = (const float*)d_in[5];
    const float* bv = (const float*)d_in[6];
    float* out = (float*)d_out;
    float* ws = (float*)d_ws;

    const size_t SZ = (size_t)BCH * NN * AANG;
    float* P     = ws;           // partial[2][n][a][x]
    float* Q     = P + 2 * SZ;
    float* Kt    = Q + SZ;       // transposed: Kt[n][j][i] (attn reads coalesced)
    float* V     = Kt + SZ;      // row-major (attn PV reads coalesced)
    float* att_t = V + SZ;
    float* WqT   = att_t;        // alias: W-transposes dead before attn writes att_t
    float* WkT   = WqT + AANG * AANG;
    float* WvT   = WkT + AANG * AANG;
    float* filt  = P;            // alias: partials dead after qkv

    radon_kernel<<<BCH * 2 * 30, 1024, 0, stream>>>(x, P, Wq, Wk, Wv, WqT, WkT, WvT);
    qkv_kernel<<<BCH * (NN / 8), 256, 0, stream>>>(P, WqT, bq, WkT, bk, WvT, bv, Q, Kt, V);
    attn_kernel<<<BCH * (NN / 8), 256, 0, stream>>>(Q, Kt, V, att_t);
    filter_kernel<<<BCH * AANG, NN, 0, stream>>>(att_t, filt);
    backproj_kernel<<<BCH * (NN / 4), 1024, 0, stream>>>(filt, out);
}